// Round 5
// baseline (488.856 us; speedup 1.0000x reference)
//
#include <hip/hip_runtime.h>
#include <cstdint>
#include <cstddef>

#define BB 16
#define NN 8192
#define DD 384
#define HH 128
#define KK 8
#define DEG 16

typedef short bf8_t __attribute__((ext_vector_type(8)));
typedef float f4_t __attribute__((ext_vector_type(4)));

__device__ __forceinline__ unsigned short f2bf(float f) {
  unsigned int u = __float_as_uint(f);
  u += 0x7FFFu + ((u >> 16) & 1u);   // RNE
  return (unsigned short)(u >> 16);
}

__device__ __forceinline__ bf8_t pack8(float4 f0, float4 f1) {
  union { unsigned short us[8]; bf8_t v; } pk;
  pk.us[0] = f2bf(f0.x); pk.us[1] = f2bf(f0.y);
  pk.us[2] = f2bf(f0.z); pk.us[3] = f2bf(f0.w);
  pk.us[4] = f2bf(f1.x); pk.us[5] = f2bf(f1.y);
  pk.us[6] = f2bf(f1.z); pk.us[7] = f2bf(f1.w);
  return pk.v;
}

// ---------------------------------------------------------------------------
// Kprep: (a) fold q@W[384:,:]+bias into per-batch base vectors;
// (b) transpose+convert W1[:384]/P1[:384] to bf16 [H][D]; (c) zero normsq.
// ---------------------------------------------------------------------------
__global__ __launch_bounds__(256) void kprep(
    const float* __restrict__ q, const float* __restrict__ W1,
    const float* __restrict__ b1, const float* __restrict__ P1,
    const float* __restrict__ pb1,
    unsigned short* __restrict__ W1t, unsigned short* __restrict__ P1t,
    float* __restrict__ base1, float* __restrict__ baseP,
    float* __restrict__ normsq)
{
  int blk = blockIdx.x, t = threadIdx.x;
  if (blk < 32) {
    int b = blk >> 1, net = blk & 1;
    const float* W = (net ? P1 : W1) + (size_t)DD * HH;   // q-half rows
    const float* qb = q + b * DD;
    int h = t & 127, half = t >> 7;
    int d0 = half * 192;
    float a0 = 0.f, a1 = 0.f, a2 = 0.f, a3 = 0.f;
    for (int d = d0; d < d0 + 192; d += 4) {
      a0 = fmaf(qb[d],     W[(size_t)d * HH + h],       a0);
      a1 = fmaf(qb[d + 1], W[(size_t)(d + 1) * HH + h], a1);
      a2 = fmaf(qb[d + 2], W[(size_t)(d + 2) * HH + h], a2);
      a3 = fmaf(qb[d + 3], W[(size_t)(d + 3) * HH + h], a3);
    }
    __shared__ float red[256];
    red[t] = (a0 + a1) + (a2 + a3);
    __syncthreads();
    if (t < 128) {
      float tot = red[t] + red[t + 128] + (net ? pb1[h] : b1[h]);
      (net ? baseP : base1)[b * HH + h] = tot;
    }
  } else {
    int e = (blk - 32) * 3072 + t;   // 32 blocks x 3072 = 2*49152 elems
    for (int it = 0; it < 12; ++it, e += 256) {
      int net = e / 49152;
      int r = e - net * 49152;
      int d = r >> 7;
      int h = r & 127;
      float v = (net ? P1 : W1)[d * HH + h];
      (net ? P1t : W1t)[h * DD + d] = f2bf(v);
    }
    if (blk == 32 && t < BB) normsq[t] = 0.f;
  }
}

// ---------------------------------------------------------------------------
// Kgemm: job = (net, h-half). Per-block B-half (64x384 bf16 = 48 KB) resident
// in LDS, XOR-swizzled, ONE barrier; depth-1 A register prefetch; 3 blocks/CU
// (24 waves) for latency hiding. Second-layer partials (relu is per-col, so
// the h-split is exact) go to rawp{0,1} / pslp{0,1}; applyscale combines.
// Same-A jobs are 512 blockIdx apart -> same XCD (round-robin %8).
// ---------------------------------------------------------------------------
__global__ __launch_bounds__(512, 6) void kgemm(
    const float* __restrict__ emb,
    const unsigned short* __restrict__ W1t, const unsigned short* __restrict__ P1t,
    const float* __restrict__ base1, const float* __restrict__ baseP,
    const float* __restrict__ W2, const float* __restrict__ P2,
    float* __restrict__ rawp0, float* __restrict__ rawp1,
    float* __restrict__ pslp0, float* __restrict__ pslp1)
{
  __shared__ __align__(16) unsigned short sB[64 * 384];    // 48 KB
  __shared__ float sW2a[64 * 9];
  __shared__ float sBase[64];
  __shared__ float sP2[64];

  const int g = blockIdx.x;
  const int job = g >> 9;                    // 0..3
  const int net = job >> 1, hh = job & 1;
  const int rowblk = g & 511;
  const int b = rowblk >> 5;
  const int rowbase = (rowblk & 31) * 256;

  const int t = threadIdx.x;
  const int w = t >> 6, lane = t & 63, q = lane >> 4, ln = lane & 15;

  // ---- stage B-half (swizzle: part p of row hl at (p ^ (hl&7))*16B) ----
  const unsigned short* Wt = (net ? P1t : W1t) + (size_t)hh * 64 * DD;
  {
    int hl = t >> 3, pb = (t & 7) * 6;
#pragma unroll
    for (int i = 0; i < 6; ++i) {
      int p = pb + i;
      uint4 v = *(const uint4*)(Wt + hl * DD + p * 8);
      *(uint4*)((char*)sB + hl * 768 + ((p ^ (hl & 7)) << 4)) = v;
    }
  }
  if (t < 64) sBase[t] = (net ? baseP : base1)[b * HH + hh * 64 + t];
  if (net == 0) {
    if (t < 512) {
      int hl = t >> 3, kk = t & 7;
      sW2a[hl * 9 + kk] = W2[(hh * 64 + hl) * KK + kk];
    }
  } else if (t >= 64 && t < 128) {
    sP2[t - 64] = P2[hh * 64 + (t - 64)];
  }

  // ---- A depth-1 prefetch ----
  const float* ar0 = emb + (size_t)(b * NN + rowbase + w * 32 + ln) * DD + q * 8;
  const float* ar1 = ar0 + (size_t)16 * DD;
  float4 pf0 = ((const float4*)ar0)[0], pf1 = ((const float4*)ar0)[1];
  float4 pf2 = ((const float4*)ar1)[0], pf3 = ((const float4*)ar1)[1];

  f4_t acc[2][4];
  f4_t zero = {0.f, 0.f, 0.f, 0.f};
#pragma unroll
  for (int i = 0; i < 4; ++i) { acc[0][i] = zero; acc[1][i] = zero; }

  __syncthreads();                           // the ONLY barrier

#pragma unroll
  for (int j = 0; j < 12; ++j) {
    bf8_t af0 = pack8(pf0, pf1);
    bf8_t af1 = pack8(pf2, pf3);
    if (j < 11) {
      const float* p0 = ar0 + (j + 1) * 32;
      const float* p1 = ar1 + (j + 1) * 32;
      pf0 = ((const float4*)p0)[0]; pf1 = ((const float4*)p0)[1];
      pf2 = ((const float4*)p1)[0]; pf3 = ((const float4*)p1)[1];
    }
    const int jb = j * 4;
#pragma unroll
    for (int ct = 0; ct < 4; ++ct) {
      const int hl = ct * 16 + ln;
      bf8_t bf = *(const bf8_t*)((const char*)sB + hl * 768 + (((jb + q) ^ (ln & 7)) << 4));
      acc[0][ct] = __builtin_amdgcn_mfma_f32_16x16x32_bf16(af0, bf, acc[0][ct], 0, 0, 0);
      acc[1][ct] = __builtin_amdgcn_mfma_f32_16x16x32_bf16(af1, bf, acc[1][ct], 0, 0, 0);
    }
  }

  // ---- epilogue: relu + partial second matmul + 16-lane reduce ----
  float* rawp = hh ? rawp1 : rawp0;
  float* pslp = hh ? pslp1 : pslp0;
#pragma unroll
  for (int grp = 0; grp < 2; ++grp) {
#pragma unroll
    for (int r = 0; r < 4; ++r) {
      const int grow = rowbase + w * 32 + grp * 16 + q * 4 + r;
      if (net == 0) {
        float s[8];
#pragma unroll
        for (int kk = 0; kk < 8; ++kk) s[kk] = 0.f;
#pragma unroll
        for (int ct = 0; ct < 4; ++ct) {
          int cl = ct * 16 + ln;
          float h1 = fmaxf(acc[grp][ct][r] + sBase[cl], 0.f);
#pragma unroll
          for (int kk = 0; kk < 8; ++kk) s[kk] = fmaf(h1, sW2a[cl * 9 + kk], s[kk]);
        }
#pragma unroll
        for (int off = 1; off < 16; off <<= 1)
#pragma unroll
          for (int kk = 0; kk < 8; ++kk) s[kk] += __shfl_xor(s[kk], off, 64);
        if (ln == 0) {
          float4* dst = (float4*)(rawp + (size_t)(b * NN + grow) * KK);
          dst[0] = make_float4(s[0], s[1], s[2], s[3]);
          dst[1] = make_float4(s[4], s[5], s[6], s[7]);
        }
      } else {
        float ps = 0.f;
#pragma unroll
        for (int ct = 0; ct < 4; ++ct) {
          int cl = ct * 16 + ln;
          float hp = fmaxf(acc[grp][ct][r] + sBase[cl], 0.f);
          ps = fmaf(hp, sP2[cl], ps);
        }
#pragma unroll
        for (int off = 1; off < 16; off <<= 1) ps += __shfl_xor(ps, off, 64);
        if (ln == 0) pslp[b * NN + grow] = ps;
      }
    }
  }
}

// ---------------------------------------------------------------------------
// applyscale: combine h-half partials, add biases, scale, write k-major
// planes: planes[k][gnode] (plane stride BB*NN floats).
// ---------------------------------------------------------------------------
__global__ __launch_bounds__(256) void applyscale(
    const float* __restrict__ raw0, const float* __restrict__ raw1,
    const float* __restrict__ psl0, const float* __restrict__ psl1,
    const float* __restrict__ b2, const float* __restrict__ pb2,
    const int* __restrict__ lab, float* __restrict__ planes)
{
  int node = blockIdx.x * 256 + threadIdx.x;   // global node 0..131071
  float ps = psl0[node] + psl1[node] + pb2[0];
  float sc = 1.f + 1.f / (1.f + __expf(-ps)) + (float)lab[node];
  const float4* r0 = (const float4*)(raw0 + (size_t)node * KK);
  const float4* r1 = (const float4*)(raw1 + (size_t)node * KK);
  float4 a0 = r0[0], a1 = r0[1], c0 = r1[0], c1 = r1[1];
  float v[8];
  v[0] = (a0.x + c0.x + b2[0]) * sc; v[1] = (a0.y + c0.y + b2[1]) * sc;
  v[2] = (a0.z + c0.z + b2[2]) * sc; v[3] = (a0.w + c0.w + b2[3]) * sc;
  v[4] = (a1.x + c1.x + b2[4]) * sc; v[5] = (a1.y + c1.y + b2[5]) * sc;
  v[6] = (a1.z + c1.z + b2[6]) * sc; v[7] = (a1.w + c1.w + b2[7]) * sc;
#pragma unroll
  for (int k = 0; k < 8; ++k) planes[(size_t)k * (BB * NN) + node] = v[k];
}

// ---------------------------------------------------------------------------
// sdiff: ALL 3 diffusion steps fused. Block = one (batch, k) plane (8192
// floats = 32 KB LDS). amps plane kept in registers as the multiplier; state
// evolves in LDS across 3 gather rounds (2 barriers/round). Per-step norms
// cancel (uniform positive scalar); only the final norm is accumulated.
// Writes u3 back over the plane in place.
// ---------------------------------------------------------------------------
__global__ __launch_bounds__(1024) void sdiff(
    const int* __restrict__ nbr, float* __restrict__ planes,
    float* __restrict__ normsq)
{
  __shared__ float sS[NN];                     // 32 KB
  const int g = blockIdx.x;                    // 128 = 16 b x 8 k
  const int b = g >> 3, k = g & 7;
  const int t = threadIdx.x;
  float* plane = planes + (size_t)k * (BB * NN) + (size_t)b * NN;
  const int* nbase = nbr + (size_t)b * NN * DEG;

  float m[8];
#pragma unroll
  for (int i = 0; i < 8; ++i) {
    float v = plane[t + i * 1024];
    m[i] = v;
    sS[t + i * 1024] = v;
  }
  __syncthreads();

  float g8[8];
#pragma unroll 1
  for (int r = 0; r < 2; ++r) {
#pragma unroll
    for (int i = 0; i < 8; ++i) {
      int n = t + i * 1024;
      const int4* nbp = (const int4*)(nbase + (size_t)n * DEG);
      int4 q0 = nbp[0], q1 = nbp[1], q2 = nbp[2], q3 = nbp[3];
      float a = sS[q0.x] + sS[q0.y] + sS[q0.z] + sS[q0.w]
              + sS[q1.x] + sS[q1.y] + sS[q1.z] + sS[q1.w]
              + sS[q2.x] + sS[q2.y] + sS[q2.z] + sS[q2.w]
              + sS[q3.x] + sS[q3.y] + sS[q3.z] + sS[q3.w];
      g8[i] = a * m[i];
    }
    __syncthreads();
#pragma unroll
    for (int i = 0; i < 8; ++i) sS[t + i * 1024] = g8[i];
    __syncthreads();
  }

  float ss = 0.f;
#pragma unroll
  for (int i = 0; i < 8; ++i) {
    int n = t + i * 1024;
    const int4* nbp = (const int4*)(nbase + (size_t)n * DEG);
    int4 q0 = nbp[0], q1 = nbp[1], q2 = nbp[2], q3 = nbp[3];
    float a = sS[q0.x] + sS[q0.y] + sS[q0.z] + sS[q0.w]
            + sS[q1.x] + sS[q1.y] + sS[q1.z] + sS[q1.w]
            + sS[q2.x] + sS[q2.y] + sS[q2.z] + sS[q2.w]
            + sS[q3.x] + sS[q3.y] + sS[q3.z] + sS[q3.w];
    plane[n] = a;
    ss += a * a;
  }
#pragma unroll
  for (int o = 1; o < 64; o <<= 1) ss += __shfl_xor(ss, o, 64);
  if ((t & 63) == 0) atomicAdd(&normsq[b], ss);
}

__global__ __launch_bounds__(256) void fout(
    const float* __restrict__ planes, const float* __restrict__ normsq,
    float* __restrict__ out)
{
  int node = blockIdx.x * 256 + threadIdx.x;   // global node
  float ns = normsq[node >> 13];
  float inv = ns > 0.f ? rsqrtf(ns) : 1.f;
  float s = 0.f;
#pragma unroll
  for (int k = 0; k < 8; ++k)
    s += fabsf(planes[(size_t)k * (BB * NN) + node]);
  out[node] = s * inv;
}

extern "C" void kernel_launch(void* const* d_in, const int* in_sizes, int n_in,
                              void* d_out, int out_size, void* d_ws, size_t ws_size,
                              hipStream_t stream) {
  const float* q   = (const float*)d_in[0];
  const float* emb = (const float*)d_in[1];
  const int*   nbr = (const int*)d_in[2];
  const int*   lab = (const int*)d_in[3];
  const float* W1  = (const float*)d_in[4];
  const float* b1  = (const float*)d_in[5];
  const float* W2  = (const float*)d_in[6];
  const float* b2  = (const float*)d_in[7];
  const float* P1  = (const float*)d_in[8];
  const float* pb1 = (const float*)d_in[9];
  const float* P2  = (const float*)d_in[10];
  const float* pb2 = (const float*)d_in[11];
  float* out = (float*)d_out;

  const size_t NK = (size_t)BB * NN * KK;     // 1,048,576 floats (4 MB)
  float* ws     = (float*)d_ws;
  float* rawp0  = ws;                         // 4 MB
  float* rawp1  = rawp0 + NK;                 // 4 MB
  float* planes = rawp1 + NK;                 // 4 MB (amps planes -> u3 in place)
  float* pslp0  = planes + NK;                // 0.5 MB
  float* pslp1  = pslp0 + (size_t)BB * NN;    // 0.5 MB
  float* base1  = pslp1 + (size_t)BB * NN;
  float* baseP  = base1 + BB * HH;
  float* normsq = baseP + BB * HH;
  unsigned short* W1t = (unsigned short*)(normsq + 16);
  unsigned short* P1t = W1t + (size_t)HH * DD;

  kprep<<<64, 256, 0, stream>>>(q, W1, b1, P1, pb1, W1t, P1t, base1, baseP, normsq);
  kgemm<<<2048, 512, 0, stream>>>(emb, W1t, P1t, base1, baseP, W2, P2,
                                  rawp0, rawp1, pslp0, pslp1);
  applyscale<<<512, 256, 0, stream>>>(rawp0, rawp1, pslp0, pslp1, b2, pb2, lab, planes);
  sdiff<<<128, 1024, 0, stream>>>(nbr, planes, normsq);
  fout<<<512, 256, 0, stream>>>(planes, normsq, out);
}

// Round 6
// 437.120 us; speedup vs baseline: 1.1184x; 1.1184x over previous
//
#include <hip/hip_runtime.h>
#include <cstdint>
#include <cstddef>

#define BB 16
#define NN 8192
#define DD 384
#define HH 128
#define KK 8
#define DEG 16

typedef short bf8_t __attribute__((ext_vector_type(8)));
typedef float f4_t __attribute__((ext_vector_type(4)));

__device__ __forceinline__ unsigned short f2bf(float f) {
  unsigned int u = __float_as_uint(f);
  u += 0x7FFFu + ((u >> 16) & 1u);   // RNE
  return (unsigned short)(u >> 16);
}

__device__ __forceinline__ bf8_t pack8(float4 f0, float4 f1) {
  union { unsigned short us[8]; bf8_t v; } pk;
  pk.us[0] = f2bf(f0.x); pk.us[1] = f2bf(f0.y);
  pk.us[2] = f2bf(f0.z); pk.us[3] = f2bf(f0.w);
  pk.us[4] = f2bf(f1.x); pk.us[5] = f2bf(f1.y);
  pk.us[6] = f2bf(f1.z); pk.us[7] = f2bf(f1.w);
  return pk.v;
}

// ---------------------------------------------------------------------------
// Kprep: (a) fold q@W[384:,:]+bias into per-batch base vectors;
// (b) transpose+convert W1[:384]/P1[:384] to bf16 [H][D]; (c) zero normsq.
// ---------------------------------------------------------------------------
__global__ __launch_bounds__(256) void kprep(
    const float* __restrict__ q, const float* __restrict__ W1,
    const float* __restrict__ b1, const float* __restrict__ P1,
    const float* __restrict__ pb1,
    unsigned short* __restrict__ W1t, unsigned short* __restrict__ P1t,
    float* __restrict__ base1, float* __restrict__ baseP,
    float* __restrict__ normsq)
{
  int blk = blockIdx.x, t = threadIdx.x;
  if (blk < 32) {
    int b = blk >> 1, net = blk & 1;
    const float* W = (net ? P1 : W1) + (size_t)DD * HH;   // q-half rows
    const float* qb = q + b * DD;
    int h = t & 127, half = t >> 7;
    int d0 = half * 192;
    float a0 = 0.f, a1 = 0.f, a2 = 0.f, a3 = 0.f;
    for (int d = d0; d < d0 + 192; d += 4) {
      a0 = fmaf(qb[d],     W[(size_t)d * HH + h],       a0);
      a1 = fmaf(qb[d + 1], W[(size_t)(d + 1) * HH + h], a1);
      a2 = fmaf(qb[d + 2], W[(size_t)(d + 2) * HH + h], a2);
      a3 = fmaf(qb[d + 3], W[(size_t)(d + 3) * HH + h], a3);
    }
    __shared__ float red[256];
    red[t] = (a0 + a1) + (a2 + a3);
    __syncthreads();
    if (t < 128) {
      float tot = red[t] + red[t + 128] + (net ? pb1[h] : b1[h]);
      (net ? baseP : base1)[b * HH + h] = tot;
    }
  } else {
    int e = (blk - 32) * 3072 + t;   // 32 blocks x 3072 = 2*49152 elems
    for (int it = 0; it < 12; ++it, e += 256) {
      int net = e / 49152;
      int r = e - net * 49152;
      int d = r >> 7;
      int h = r & 127;
      float v = (net ? P1 : W1)[d * HH + h];
      (net ? P1t : W1t)[h * DD + d] = f2bf(v);
    }
    if (blk == 32 && t < BB) normsq[t] = 0.f;
  }
}

// ---------------------------------------------------------------------------
// Kgemm: job = (net, h-half), 48 KB LDS B-half, 3 blocks/CU.
// KEY (r5 fix): the 4 jobs sharing an A row-block sit at blockIdx g, g+8,
// g+16, g+24 -> same XCD under round-robin, concurrent in time -> A is read
// once from HBM and 3x from that XCD's L2 (r4 evidence: FETCH 100 MB).
// ---------------------------------------------------------------------------
__global__ __launch_bounds__(512, 6) void kgemm(
    const float* __restrict__ emb,
    const unsigned short* __restrict__ W1t, const unsigned short* __restrict__ P1t,
    const float* __restrict__ base1, const float* __restrict__ baseP,
    const float* __restrict__ W2, const float* __restrict__ P2,
    float* __restrict__ rawp0, float* __restrict__ rawp1,
    float* __restrict__ pslp0, float* __restrict__ pslp1)
{
  __shared__ __align__(16) unsigned short sB[64 * 384];    // 48 KB
  __shared__ float sW2a[64 * 9];
  __shared__ float sBase[64];
  __shared__ float sP2[64];

  const int g = blockIdx.x;
  const int slot = g & 7;                    // XCD under round-robin
  const int job = (g >> 3) & 3;              // partners 8 apart -> same XCD
  const int net = job >> 1, hh = job & 1;
  const int wid = (g >> 5) * 8 + slot;       // 0..511 row-block id
  const int b = wid >> 5;
  const int rowbase = (wid & 31) * 256;

  const int t = threadIdx.x;
  const int w = t >> 6, lane = t & 63, q = lane >> 4, ln = lane & 15;

  // ---- stage B-half (swizzle: part p of row hl at (p ^ (hl&7))*16B) ----
  const unsigned short* Wt = (net ? P1t : W1t) + (size_t)hh * 64 * DD;
  {
    int hl = t >> 3, pb = (t & 7) * 6;
#pragma unroll
    for (int i = 0; i < 6; ++i) {
      int p = pb + i;
      uint4 v = *(const uint4*)(Wt + hl * DD + p * 8);
      *(uint4*)((char*)sB + hl * 768 + ((p ^ (hl & 7)) << 4)) = v;
    }
  }
  if (t < 64) sBase[t] = (net ? baseP : base1)[b * HH + hh * 64 + t];
  if (net == 0) {
    if (t < 512) {
      int hl = t >> 3, kk = t & 7;
      sW2a[hl * 9 + kk] = W2[(hh * 64 + hl) * KK + kk];
    }
  } else if (t >= 64 && t < 128) {
    sP2[t - 64] = P2[hh * 64 + (t - 64)];
  }

  // ---- A depth-1 prefetch ----
  const float* ar0 = emb + (size_t)(b * NN + rowbase + w * 32 + ln) * DD + q * 8;
  const float* ar1 = ar0 + (size_t)16 * DD;
  float4 pf0 = ((const float4*)ar0)[0], pf1 = ((const float4*)ar0)[1];
  float4 pf2 = ((const float4*)ar1)[0], pf3 = ((const float4*)ar1)[1];

  f4_t acc[2][4];
  f4_t zero = {0.f, 0.f, 0.f, 0.f};
#pragma unroll
  for (int i = 0; i < 4; ++i) { acc[0][i] = zero; acc[1][i] = zero; }

  __syncthreads();                           // the ONLY barrier

#pragma unroll
  for (int j = 0; j < 12; ++j) {
    bf8_t af0 = pack8(pf0, pf1);
    bf8_t af1 = pack8(pf2, pf3);
    if (j < 11) {
      const float* p0 = ar0 + (j + 1) * 32;
      const float* p1 = ar1 + (j + 1) * 32;
      pf0 = ((const float4*)p0)[0]; pf1 = ((const float4*)p0)[1];
      pf2 = ((const float4*)p1)[0]; pf3 = ((const float4*)p1)[1];
    }
    const int jb = j * 4;
#pragma unroll
    for (int ct = 0; ct < 4; ++ct) {
      const int hl = ct * 16 + ln;
      bf8_t bf = *(const bf8_t*)((const char*)sB + hl * 768 + (((jb + q) ^ (ln & 7)) << 4));
      acc[0][ct] = __builtin_amdgcn_mfma_f32_16x16x32_bf16(af0, bf, acc[0][ct], 0, 0, 0);
      acc[1][ct] = __builtin_amdgcn_mfma_f32_16x16x32_bf16(af1, bf, acc[1][ct], 0, 0, 0);
    }
  }

  // ---- epilogue: relu + partial second matmul + 16-lane reduce ----
  float* rawp = hh ? rawp1 : rawp0;
  float* pslp = hh ? pslp1 : pslp0;
#pragma unroll
  for (int grp = 0; grp < 2; ++grp) {
#pragma unroll
    for (int r = 0; r < 4; ++r) {
      const int grow = rowbase + w * 32 + grp * 16 + q * 4 + r;
      if (net == 0) {
        float s[8];
#pragma unroll
        for (int kk = 0; kk < 8; ++kk) s[kk] = 0.f;
#pragma unroll
        for (int ct = 0; ct < 4; ++ct) {
          int cl = ct * 16 + ln;
          float h1 = fmaxf(acc[grp][ct][r] + sBase[cl], 0.f);
#pragma unroll
          for (int kk = 0; kk < 8; ++kk) s[kk] = fmaf(h1, sW2a[cl * 9 + kk], s[kk]);
        }
#pragma unroll
        for (int off = 1; off < 16; off <<= 1)
#pragma unroll
          for (int kk = 0; kk < 8; ++kk) s[kk] += __shfl_xor(s[kk], off, 64);
        if (ln == 0) {
          float4* dst = (float4*)(rawp + (size_t)(b * NN + grow) * KK);
          dst[0] = make_float4(s[0], s[1], s[2], s[3]);
          dst[1] = make_float4(s[4], s[5], s[6], s[7]);
        }
      } else {
        float ps = 0.f;
#pragma unroll
        for (int ct = 0; ct < 4; ++ct) {
          int cl = ct * 16 + ln;
          float hp = fmaxf(acc[grp][ct][r] + sBase[cl], 0.f);
          ps = fmaf(hp, sP2[cl], ps);
        }
#pragma unroll
        for (int off = 1; off < 16; off <<= 1) ps += __shfl_xor(ps, off, 64);
        if (ln == 0) pslp[b * NN + grow] = ps;
      }
    }
  }
}

// ---------------------------------------------------------------------------
// applyscale: combine h-half partials, add biases, scale, write k-pair-major
// float2 planes: planes[kp][gnode] (plane stride BB*NN float2).
// ---------------------------------------------------------------------------
__global__ __launch_bounds__(256) void applyscale(
    const float* __restrict__ raw0, const float* __restrict__ raw1,
    const float* __restrict__ psl0, const float* __restrict__ psl1,
    const float* __restrict__ b2, const float* __restrict__ pb2,
    const int* __restrict__ lab, float* __restrict__ planes)
{
  int node = blockIdx.x * 256 + threadIdx.x;   // global node 0..131071
  float ps = psl0[node] + psl1[node] + pb2[0];
  float sc = 1.f + 1.f / (1.f + __expf(-ps)) + (float)lab[node];
  const float4* r0 = (const float4*)(raw0 + (size_t)node * KK);
  const float4* r1 = (const float4*)(raw1 + (size_t)node * KK);
  float4 a0 = r0[0], a1 = r0[1], c0 = r1[0], c1 = r1[1];
  float2* p = (float2*)planes;
  p[0 * (BB * NN) + node] = make_float2((a0.x + c0.x + b2[0]) * sc,
                                        (a0.y + c0.y + b2[1]) * sc);
  p[1 * (BB * NN) + node] = make_float2((a0.z + c0.z + b2[2]) * sc,
                                        (a0.w + c0.w + b2[3]) * sc);
  p[2 * (BB * NN) + node] = make_float2((a1.x + c1.x + b2[4]) * sc,
                                        (a1.y + c1.y + b2[5]) * sc);
  p[3 * (BB * NN) + node] = make_float2((a1.z + c1.z + b2[6]) * sc,
                                        (a1.w + c1.w + b2[7]) * sc);
}

// ---------------------------------------------------------------------------
// Diffusion step via LDS-resident plane (r4-proven). Block = (batch b,
// k-pair kp, replica rep of 8). Stage the 64 KB plane coalesced, one
// barrier, gather 16 neighbors/node from LDS (ds_read_b64). Per-step norms
// cancel; only the final step accumulates the norm.
// ---------------------------------------------------------------------------
template<bool MUL, bool NRM>
__global__ __launch_bounds__(256) void sgl(
    const int* __restrict__ nbr, const float* __restrict__ src,
    const float* __restrict__ mult, float* __restrict__ out,
    float* __restrict__ normsq)
{
  __shared__ float2 sS[NN];                    // 64 KB
  const int g = blockIdx.x;
  const int kp = g & 3;
  const int rep = (g >> 2) & 7;
  const int b = g >> 5;
  const int t = threadIdx.x;

  const size_t pb = (size_t)kp * (BB * NN) + (size_t)b * NN;
  {
    const float4* p4 = (const float4*)((const float2*)src + pb);
    float4* s4 = (float4*)sS;
#pragma unroll
    for (int i = 0; i < 16; ++i) s4[t + i * 256] = p4[t + i * 256];
  }
  __syncthreads();

  const float2* mplane = (const float2*)mult + pb;
  float2* oplane = (float2*)out + pb;
  float ssacc = 0.f;
#pragma unroll
  for (int u = 0; u < 4; ++u) {
    int n = rep * 1024 + u * 256 + t;
    const int4* nbp = (const int4*)(nbr + ((size_t)b * NN + n) * DEG);
    int4 q0 = nbp[0], q1 = nbp[1], q2 = nbp[2], q3 = nbp[3];
    float ax = 0.f, ay = 0.f;
    float2 v;
    v = sS[q0.x]; ax += v.x; ay += v.y;
    v = sS[q0.y]; ax += v.x; ay += v.y;
    v = sS[q0.z]; ax += v.x; ay += v.y;
    v = sS[q0.w]; ax += v.x; ay += v.y;
    v = sS[q1.x]; ax += v.x; ay += v.y;
    v = sS[q1.y]; ax += v.x; ay += v.y;
    v = sS[q1.z]; ax += v.x; ay += v.y;
    v = sS[q1.w]; ax += v.x; ay += v.y;
    v = sS[q2.x]; ax += v.x; ay += v.y;
    v = sS[q2.y]; ax += v.x; ay += v.y;
    v = sS[q2.z]; ax += v.x; ay += v.y;
    v = sS[q2.w]; ax += v.x; ay += v.y;
    v = sS[q3.x]; ax += v.x; ay += v.y;
    v = sS[q3.y]; ax += v.x; ay += v.y;
    v = sS[q3.z]; ax += v.x; ay += v.y;
    v = sS[q3.w]; ax += v.x; ay += v.y;
    if (MUL) { float2 m = mplane[n]; ax *= m.x; ay *= m.y; }
    oplane[n] = make_float2(ax, ay);
    if (NRM) ssacc += ax * ax + ay * ay;
  }
  if (NRM) {
#pragma unroll
    for (int o = 1; o < 64; o <<= 1) ssacc += __shfl_xor(ssacc, o, 64);
    if ((t & 63) == 0) atomicAdd(&normsq[b], ssacc);
  }
}

__global__ __launch_bounds__(256) void fout(
    const float* __restrict__ u, const float* __restrict__ normsq,
    float* __restrict__ out)
{
  int node = blockIdx.x * 256 + threadIdx.x;   // global node
  float ns = normsq[node >> 13];
  float inv = ns > 0.f ? rsqrtf(ns) : 1.f;
  const float2* p = (const float2*)u;
  float2 v0 = p[0 * (BB * NN) + node];
  float2 v1 = p[1 * (BB * NN) + node];
  float2 v2 = p[2 * (BB * NN) + node];
  float2 v3 = p[3 * (BB * NN) + node];
  out[node] = (fabsf(v0.x) + fabsf(v0.y) + fabsf(v1.x) + fabsf(v1.y) +
               fabsf(v2.x) + fabsf(v2.y) + fabsf(v3.x) + fabsf(v3.y)) * inv;
}

extern "C" void kernel_launch(void* const* d_in, const int* in_sizes, int n_in,
                              void* d_out, int out_size, void* d_ws, size_t ws_size,
                              hipStream_t stream) {
  const float* q   = (const float*)d_in[0];
  const float* emb = (const float*)d_in[1];
  const int*   nbr = (const int*)d_in[2];
  const int*   lab = (const int*)d_in[3];
  const float* W1  = (const float*)d_in[4];
  const float* b1  = (const float*)d_in[5];
  const float* W2  = (const float*)d_in[6];
  const float* b2  = (const float*)d_in[7];
  const float* P1  = (const float*)d_in[8];
  const float* pb1 = (const float*)d_in[9];
  const float* P2  = (const float*)d_in[10];
  const float* pb2 = (const float*)d_in[11];
  float* out = (float*)d_out;

  const size_t NK = (size_t)BB * NN * KK;     // 1,048,576 floats (4 MB)
  float* ws     = (float*)d_ws;
  float* rawp0  = ws;                         // 4 MB, later u1m planes buf
  float* rawp1  = rawp0 + NK;                 // 4 MB, later u2m planes buf
  float* planes = rawp1 + NK;                 // 4 MB (amps planes -> u3)
  float* pslp0  = planes + NK;                // 0.5 MB
  float* pslp1  = pslp0 + (size_t)BB * NN;    // 0.5 MB
  float* base1  = pslp1 + (size_t)BB * NN;
  float* baseP  = base1 + BB * HH;
  float* normsq = baseP + BB * HH;
  unsigned short* W1t = (unsigned short*)(normsq + 16);
  unsigned short* P1t = W1t + (size_t)HH * DD;

  kprep<<<64, 256, 0, stream>>>(q, W1, b1, P1, pb1, W1t, P1t, base1, baseP, normsq);
  kgemm<<<2048, 512, 0, stream>>>(emb, W1t, P1t, base1, baseP, W2, P2,
                                  rawp0, rawp1, pslp0, pslp1);
  applyscale<<<512, 256, 0, stream>>>(rawp0, rawp1, pslp0, pslp1, b2, pb2, lab, planes);
  // planes = amps (kp-major float2). Diffusion (norms cancel until last):
  sgl<true,  false><<<512, 256, 0, stream>>>(nbr, planes, planes, rawp0, normsq); // u1m
  sgl<true,  false><<<512, 256, 0, stream>>>(nbr, rawp0, planes, rawp1, normsq);  // u2m
  sgl<false, true ><<<512, 256, 0, stream>>>(nbr, rawp1, rawp1, planes, normsq);  // u3
  fout<<<512, 256, 0, stream>>>(planes, normsq, out);
}